// Round 1
// baseline (605.684 us; speedup 1.0000x reference)
//
#include <hip/hip_runtime.h>

// Problem constants (from reference)
#define NBATCH 4096
#define NF     32
#define DIM    64
#define NPAIRS 496

// Tiling: one block = one (pair, 128-batch-row tile)
#define MTILE  128
#define LDAP   72    // LDS row stride in f16 elems: 64 + 8 pad (144 B, 16B-aligned, 2-way bank alias = free)

typedef _Float16 half8 __attribute__((ext_vector_type(8)));
typedef _Float16 half4v __attribute__((ext_vector_type(4)));
typedef float    floatx4 __attribute__((ext_vector_type(4)));

__global__ __launch_bounds__(256, 4)
void bilinear_mfma(const float* __restrict__ x, const float* __restrict__ W,
                   float* __restrict__ out) {
    // W[p] tile (64x64) and x_i tile (128x64) in f16
    __shared__ _Float16 sW[DIM * LDAP];     //  9216 B
    __shared__ _Float16 sA[MTILE * LDAP];   // 18432 B

    const int tid  = threadIdx.x;
    const int lane = tid & 63;
    const int wv   = tid >> 6;      // wave id 0..3
    const int lrow = lane & 15;
    const int quad = lane >> 4;

    const int p  = blockIdx.x % NPAIRS;   // pair-inner: consecutive blocks share x batch tile in L2
    const int bt = blockIdx.x / NPAIRS;
    const int b0 = bt * MTILE;

    // decode lexicographic combinations(range(32), 2): p -> (fi, fj)
    int fi = 0, rem = p;
    while (rem >= NF - 1 - fi) { rem -= NF - 1 - fi; ++fi; }
    const int fj = fi + 1 + rem;

    // ---- stage W[p] (64x64 fp32) -> sW (f16), float4 coalesced ----
    const float* Wp = W + (size_t)p * (DIM * DIM);
    #pragma unroll
    for (int it = 0; it < 4; ++it) {
        int idx = tid + 256 * it;          // float4 index 0..1023
        int o   = idx >> 4;                // 16 float4 per row
        int c4  = (idx & 15) << 2;
        const float4 v = *(const float4*)(Wp + o * DIM + c4);
        half4v hv;
        hv[0] = (_Float16)v.x; hv[1] = (_Float16)v.y;
        hv[2] = (_Float16)v.z; hv[3] = (_Float16)v.w;
        *(half4v*)(&sW[o * LDAP + c4]) = hv;   // 8B store, 8B-aligned
    }

    // ---- stage x_i tile (128x64 fp32) -> sA (f16) ----
    #pragma unroll
    for (int it = 0; it < 8; ++it) {
        int idx = tid + 256 * it;          // float4 index 0..2047
        int r   = idx >> 4;
        int c4  = (idx & 15) << 2;
        const float4 v = *(const float4*)(x + ((size_t)(b0 + r) * NF + fi) * DIM + c4);
        half4v hv;
        hv[0] = (_Float16)v.x; hv[1] = (_Float16)v.y;
        hv[2] = (_Float16)v.z; hv[3] = (_Float16)v.w;
        *(half4v*)(&sA[r * LDAP + c4]) = hv;
    }
    __syncthreads();

    // ---- MFMA: wave wv covers M rows [wv*32, wv*32+32), all 64 N cols ----
    // 2 M-tiles x 4 N-tiles of 16x16, K=64 in 2 steps of 32
    floatx4 acc[2][4] = {};
    #pragma unroll
    for (int ks = 0; ks < 2; ++ks) {
        half8 af[2], bf[4];
        #pragma unroll
        for (int mt = 0; mt < 2; ++mt)
            af[mt] = *(const half8*)(&sA[(wv * 32 + mt * 16 + lrow) * LDAP + ks * 32 + quad * 8]);
        #pragma unroll
        for (int nt = 0; nt < 4; ++nt)
            bf[nt] = *(const half8*)(&sW[(nt * 16 + lrow) * LDAP + ks * 32 + quad * 8]);
        #pragma unroll
        for (int mt = 0; mt < 2; ++mt)
            #pragma unroll
            for (int nt = 0; nt < 4; ++nt)
                acc[mt][nt] = __builtin_amdgcn_mfma_f32_16x16x32_f16(af[mt], bf[nt], acc[mt][nt], 0, 0, 0);
    }

    // ---- epilogue: multiply by x_j (global, cached) and non-temporal store ----
    // C/D layout: col = lane&15, row = quad*4 + reg
    #pragma unroll
    for (int mt = 0; mt < 2; ++mt) {
        #pragma unroll
        for (int r = 0; r < 4; ++r) {
            const int row = wv * 32 + mt * 16 + quad * 4 + r;     // local batch row
            const size_t b = (size_t)(b0 + row);
            const float* xjrow = x + (b * NF + fj) * DIM;
            float* orow = out + b * (NPAIRS * DIM) + (size_t)p * DIM;
            #pragma unroll
            for (int nt = 0; nt < 4; ++nt) {
                const int col = nt * 16 + lrow;
                __builtin_nontemporal_store(acc[mt][nt][r] * xjrow[col], &orow[col]);
            }
        }
    }
}

extern "C" void kernel_launch(void* const* d_in, const int* in_sizes, int n_in,
                              void* d_out, int out_size, void* d_ws, size_t ws_size,
                              hipStream_t stream) {
    const float* x = (const float*)d_in[0];   // (4096, 32, 64) fp32
    const float* W = (const float*)d_in[1];   // (496, 64, 64) fp32
    float* out = (float*)d_out;               // (4096, 496, 64) fp32

    dim3 grid(NPAIRS * (NBATCH / MTILE));     // 496 * 32 = 15872 blocks
    bilinear_mfma<<<grid, 256, 0, stream>>>(x, W, out);
}